// Round 4
// baseline (161.233 us; speedup 1.0000x reference)
//
#include <hip/hip_runtime.h>

#define NF   256   // IN_F
#define HD   256   // H*D
#define NH   4
#define DH   64
#define WINS 128   // WIN
#define HALFW 64
#define TOPK 32
#define GR   8     // rows per gemm block

// ------------- fused Q/K projection: X[n,256] @ W[256,256] + b -------------
// grid (n/GR, 2): y==0 -> Q row-major; y==1 -> K written TRANSPOSED (KT[c][node]).
// X staged in LDS (broadcast b128 reads); W dword loads coalesced per wave.
__global__ __launch_bounds__(256) void qk_gemm_kernel(
    const float* __restrict__ X,
    const float* __restrict__ Wq, const float* __restrict__ bq,
    const float* __restrict__ Wk, const float* __restrict__ bk,
    float* __restrict__ Qb, float* __restrict__ Kt, int n)
{
    const bool isK = (blockIdx.y != 0);
    const float* W   = isK ? Wk : Wq;
    const float* bia = isK ? bk : bq;

    __shared__ float feat[GR][NF];
    const int rowBase = blockIdx.x * GR;
    const int t = threadIdx.x;

    {   // stage X tile: 8 rows x 256 = 512 float4s, 2 per thread, coalesced
        const float4* src = (const float4*)(X + (size_t)rowBase * NF);
        float4* dst = (float4*)&feat[0][0];
        dst[t]       = src[t];
        dst[t + 256] = src[t + 256];
    }
    __syncthreads();

    float acc[GR];
#pragma unroll
    for (int r = 0; r < GR; ++r) acc[r] = 0.f;

#pragma unroll 4
    for (int k = 0; k < NF; k += 4) {
        float w0 = W[(size_t)(k + 0) * HD + t];
        float w1 = W[(size_t)(k + 1) * HD + t];
        float w2 = W[(size_t)(k + 2) * HD + t];
        float w3 = W[(size_t)(k + 3) * HD + t];
#pragma unroll
        for (int r = 0; r < GR; ++r) {
            float4 f = *(const float4*)&feat[r][k];   // same-addr broadcast
            acc[r] += f.x * w0 + f.y * w1 + f.z * w2 + f.w * w3;
        }
    }
    float bias = bia[t];

    if (!isK) {
#pragma unroll
        for (int r = 0; r < GR; ++r)
            Qb[(size_t)(rowBase + r) * HD + t] = acc[r] + bias;
    } else {
        // transposed store: KT[col t][rowBase..rowBase+7], 2 float4s per thread
        float4* o = (float4*)(Kt + (size_t)t * n + rowBase);
        o[0] = make_float4(acc[0] + bias, acc[1] + bias, acc[2] + bias, acc[3] + bias);
        o[1] = make_float4(acc[4] + bias, acc[5] + bias, acc[6] + bias, acc[7] + bias);
    }
}

// ---- per-node windowed attention + top-32 + fused full-row write ----
// 256 threads = 4 waves; wave = head h; lane l owns slots {l, l+64}.
// Scores via KT: per d, two coalesced dword loads + LDS-broadcast q[d].
// No cross-lane reduction in the score phase at all.
__global__ __launch_bounds__(256) void attn_topk_kernel(
    const float* __restrict__ Q,
    const float* __restrict__ KT,
    const int* __restrict__ nnpg, int n_graphs,
    const int* __restrict__ nrel,
    float* __restrict__ out, int n)
{
    const int i    = blockIdx.x;
    const int t    = threadIdx.x;
    const int wave = t >> 6;
    const int lane = t & 63;

    __shared__ float qs[HD];
    __shared__ float pr[NH][WINS];
    __shared__ float attnv[WINS];
    __shared__ float slotval[WINS];

    // segment bounds: tile(nnpg, R) -> cumsum -> searchsorted(right)
    int R = nrel[0];
    int total = n_graphs * R;
    int seg_start = 0, seg_end = n;
    int cum = 0;
    for (int e = 0; e < total; ++e) {
        int sz = nnpg[e % n_graphs];
        int nc = cum + sz;
        if (i < nc) { seg_start = cum; seg_end = nc; break; }
        cum = nc;
    }
    const int start = max(seg_start, i - HALFW);
    const int end   = min(seg_end,   i + HALFW);
    const int win   = end - start;            // >= 64 (segments >= 128 nodes)

    qs[t] = Q[(size_t)i * HD + t];
    __syncthreads();

    const bool v0 = (lane      < win);
    const bool v1 = (lane + 64 < win);
    const int  j0 = v0 ? (start + lane)      : start;   // clamped: stays in-row
    const int  j1 = v1 ? (start + lane + 64) : start;

    const float* kcol = KT + (size_t)(wave * DH) * n;
    const float* qh   = qs + wave * DH;

    float a0 = 0.f, a1 = 0.f;
#pragma unroll 8
    for (int d = 0; d < DH; ++d) {
        float qd = qh[d];                      // LDS broadcast
        const float* col = kcol + (size_t)d * n;
        a0 += qd * col[j0];                    // coalesced dword across lanes
        a1 += qd * col[j1];
    }
    a0 = v0 ? a0 * 0.25f : 0.f;    // /sqrt(64)/tau; padded slots exactly 0
    a1 = v1 ? a1 * 0.25f : 0.f;

    // per-head softmax over the full 128-slot window (incl. zero padding)
    float mx = fmaxf(a0, a1);
#pragma unroll
    for (int off = 32; off > 0; off >>= 1) mx = fmaxf(mx, __shfl_xor(mx, off));
    float e0 = expf(a0 - mx), e1 = expf(a1 - mx);
    float sm = e0 + e1;
#pragma unroll
    for (int off = 32; off > 0; off >>= 1) sm += __shfl_xor(sm, off);
    pr[wave][lane]      = e0 / sm;
    pr[wave][lane + 64] = e1 / sm;
    __syncthreads();

    // mean over heads; invalid slots excluded from top-k
    if (t < WINS) {
        float a = 0.25f * (pr[0][t] + pr[1][t] + pr[2][t] + pr[3][t]);
        attnv[t] = (t < win) ? a : -1.0f;
    }
    __syncthreads();

    // stable top-32 rank count (lower index wins ties, like lax.top_k)
    if (t < WINS) {
        float v = attnv[t];
        int cnt = 0;
#pragma unroll
        for (int j4 = 0; j4 < WINS / 4; ++j4) {
            float4 a4 = *(const float4*)&attnv[j4 * 4];
            int jb = j4 * 4;
            cnt += (a4.x > v) || (a4.x == v && (jb + 0) < t);
            cnt += (a4.y > v) || (a4.y == v && (jb + 1) < t);
            cnt += (a4.z > v) || (a4.z == v && (jb + 2) < t);
            cnt += (a4.w > v) || (a4.w == v && (jb + 3) < t);
        }
        slotval[t] = (t < win && cnt < TOPK) ? 1.0f : 0.0f;
    }
    __syncthreads();

    // fused full-row write: zeros + window values, float4 stores
    float4* orow = (float4*)(out + (size_t)i * n);
    const int n4 = n >> 2;
    for (int c4 = t; c4 < n4; c4 += 256) {
        int c = c4 << 2;
        float4 v4 = make_float4(0.f, 0.f, 0.f, 0.f);
        if (c + 3 >= start && c < end) {
            int o = c - start;
            if (o     >= 0 && o     < WINS) v4.x = slotval[o];
            if (o + 1 >= 0 && o + 1 < WINS) v4.y = slotval[o + 1];
            if (o + 2 >= 0 && o + 2 < WINS) v4.z = slotval[o + 2];
            if (o + 3 >= 0 && o + 3 < WINS) v4.w = slotval[o + 3];
        }
        orow[c4] = v4;
    }
}

extern "C" void kernel_launch(void* const* d_in, const int* in_sizes, int n_in,
                              void* d_out, int out_size, void* d_ws, size_t ws_size,
                              hipStream_t stream)
{
    const float* X  = (const float*)d_in[0];
    const float* Wq = (const float*)d_in[1];
    const float* bq = (const float*)d_in[2];
    const float* Wk = (const float*)d_in[3];
    const float* bk = (const float*)d_in[4];
    const int* nnpg = (const int*)d_in[5];
    const int* nrel = (const int*)d_in[6];

    const int n = in_sizes[0] / NF;
    const int n_graphs = in_sizes[5];

    float* Qb = (float*)d_ws;                 // [n][256] row-major
    float* Kt = Qb + (size_t)n * HD;          // [256][n] transposed
    float* out = (float*)d_out;

    dim3 gg(n / GR, 2);
    qk_gemm_kernel<<<gg, 256, 0, stream>>>(X, Wq, bq, Wk, bk, Qb, Kt, n);
    attn_topk_kernel<<<n, 256, 0, stream>>>(Qb, Kt, nnpg, n_graphs, nrel, out, n);
}